// Round 3
// baseline (1130.603 us; speedup 1.0000x reference)
//
#include <hip/hip_runtime.h>
#include <hip/hip_bf16.h>
#include <stdint.h>

// ---------------- constants ----------------
#define DIMC 512
#define HEADS 16
#define HEAD_DIM 32
#define NTOK 49            // tokens per window (7x7)
#define SCALE 0.17677669529663687f   // 1/sqrt(32)

typedef unsigned short u16;
typedef short bf16x8 __attribute__((ext_vector_type(8)));
typedef float f32x4 __attribute__((ext_vector_type(4)));
typedef u16 u16x8 __attribute__((ext_vector_type(8)));

#define MFMA16(a, b, c) __builtin_amdgcn_mfma_f32_16x16x32_bf16((a), (b), (c), 0, 0, 0)

__device__ __forceinline__ u16 f2bf(float f) {
  __hip_bfloat16 h = __float2bfloat16(f);   // RNE
  u16 u;
  __builtin_memcpy(&u, &h, 2);
  return u;
}

// async global->LDS, 16 bytes per lane (wave-uniform LDS base + lane*16)
__device__ __forceinline__ void gld16(const void* g, void* l) {
  __builtin_amdgcn_global_load_lds(
      (const __attribute__((address_space(1))) uint32_t*)g,
      (__attribute__((address_space(3))) uint32_t*)l, 16, 0, 0);
}

// ---------------- fp32 -> bf16 convert (grid-stride, 8 elems/thread/iter) ----
__global__ void cvt_f32_bf16(const float* __restrict__ in, u16* __restrict__ out, int n) {
  const int stride = gridDim.x * blockDim.x;
  for (int i = blockIdx.x * blockDim.x + threadIdx.x; i * 8 < n; i += stride) {
    const float4 v0 = ((const float4*)(in + i * 8))[0];
    const float4 v1 = ((const float4*)(in + i * 8))[1];
    u16x8 r;
    r[0] = f2bf(v0.x); r[1] = f2bf(v0.y); r[2] = f2bf(v0.z); r[3] = f2bf(v0.w);
    r[4] = f2bf(v1.x); r[5] = f2bf(v1.y); r[6] = f2bf(v1.z); r[7] = f2bf(v1.w);
    *(u16x8*)(out + i * 8) = r;
  }
}

// ---------------- bias+mask precompute: [64][16][64][64] fp32, pad = -1e30 ----
__global__ void biasmask_kernel(const float* __restrict__ table, const float* __restrict__ mask,
                                float* __restrict__ bm) {
  const int wm = blockIdx.x >> 4;   // 0..63  (window-in-image)
  const int h  = blockIdx.x & 15;   // 0..15
  for (int e = threadIdx.x; e < 4096; e += 256) {
    const int i = e >> 6, j = e & 63;
    float v;
    if (i < NTOK && j < NTOK) {
      const int yi = i / 7, xi = i % 7, yj = j / 7, xj = j % 7;
      const int idx = (yi - yj + 6) * 13 + (xi - xj + 6);
      v = table[idx * HEADS + h] + mask[wm * (NTOK * NTOK) + i * NTOK + j];
    } else {
      v = -1e30f;   // kill padded keys in softmax; padded queries harmless
    }
    bm[(size_t)blockIdx.x * 4096 + e] = v;
  }
}

// swizzled element address within a 256x32 bf16 operand tile packed in 8192 u16.
// chunk-XOR (row&7-folded) -> conflict-free ds_read_b128 (proven R2, conflicts==0)
__device__ __forceinline__ int swz_addr(int row, int col) {
  return (row >> 1) * 64 + (((((row & 1) << 2) | (col >> 3)) ^ ((row >> 1) & 7)) << 3) + (col & 7);
}

// ---------------- GEMM: C[M,N] = A[M,K] @ B[N,K]^T + bias (all bf16 in) ------
// 256x256 tile, BK=32, 8 waves (2M x 4N), per-wave 128x64 output.
// Double-buffered LDS (64 KB), 4-phase/K-tile schedule: per phase
// {ds_read frags | issue next-tile global_load_lds -> s_barrier -> setprio(1)
//  -> 16 MFMA -> setprio(0) -> s_barrier}; vmcnt drained ONCE per K-tile
// (loads issued ~2 phases early stay in flight across barriers). T1+T2+T3/T4+T5.
template<bool OUT_BF16, bool QKV_SCALE>
__launch_bounds__(512, 2)
__global__ void gemm8(const u16* __restrict__ Ap, const u16* __restrict__ Bp,
                      const float* __restrict__ bias, void* __restrict__ Cp,
                      int M, int N, int K, int nxt) {
  __shared__ u16 As[2][8192];
  __shared__ u16 Bs[2][8192];
  const int t = threadIdx.x;
  const int lane = t & 63;
  const int wv = t >> 6;          // 0..7
  const int wr = wv >> 2;         // A-half (0/1): rows wr*128..+128
  const int wc = wv & 3;          // B-strip: cols wc*64..+64
  const int lr = lane & 15, lg = lane >> 4;

  // XCD-chunked bijective swizzle (grid % 8 == 0 for all our launches)
  const int q = gridDim.x >> 3;
  const int l = (blockIdx.x & 7) * q + (blockIdx.x >> 3);
  const int bm0 = (l / nxt) * 256;
  const int bn0 = (l % nxt) * 256;

  f32x4 acc[8][4] = {};

  // staging: 1024 chunks per operand per K-tile; 2 per thread (c = t + 512k).
  // LDS dest linear (c*16B); inverse-swizzle applied to the GLOBAL source.
  const u16* agp[2];
  const u16* bgp[2];
  int ldst[2];
#pragma unroll
  for (int kc = 0; kc < 2; ++kc) {
    const int c = t + (kc << 9);
    const int r2 = c >> 3;
    const int sub = (c & 7) ^ (r2 & 7);
    const int row = (r2 << 1) | (sub >> 2);
    const int col = (sub & 3) << 3;
    agp[kc] = Ap + (size_t)(bm0 + row) * K + col;
    bgp[kc] = Bp + (size_t)(bn0 + row) * K + col;
    ldst[kc] = c * 8;
  }

  // prologue: stage K-tile 0 into buf 0, full drain once
#pragma unroll
  for (int kc = 0; kc < 2; ++kc) {
    gld16(agp[kc], &As[0][ldst[kc]]);
    gld16(bgp[kc], &Bs[0][ldst[kc]]);
    agp[kc] += 32; bgp[kc] += 32;
  }
  asm volatile("s_waitcnt vmcnt(0)" ::: "memory");
  __builtin_amdgcn_s_barrier();

  const int nK = K >> 5;
  for (int kt = 0; kt < nK; ++kt) {
    const int buf = kt & 1;
    const u16* Asb = &As[buf][0];
    const u16* Bsb = &Bs[buf][0];

    // ---- phase 0: read B frags (4) + A frags mi0..3 (4); stage next tile
    bf16x8 bfr[4], af[4];
#pragma unroll
    for (int nj = 0; nj < 4; ++nj)
      bfr[nj] = *(const bf16x8*)&Bsb[swz_addr(wc * 64 + nj * 16 + lr, lg * 8)];
#pragma unroll
    for (int mi = 0; mi < 4; ++mi)
      af[mi] = *(const bf16x8*)&Asb[swz_addr(wr * 128 + mi * 16 + lr, lg * 8)];
    if (kt + 1 < nK) {
#pragma unroll
      for (int kc = 0; kc < 2; ++kc) {
        gld16(agp[kc], &As[buf ^ 1][ldst[kc]]);
        gld16(bgp[kc], &Bs[buf ^ 1][ldst[kc]]);
        agp[kc] += 32; bgp[kc] += 32;
      }
    }
    __builtin_amdgcn_s_barrier();
    __builtin_amdgcn_s_setprio(1);
#pragma unroll
    for (int mi = 0; mi < 4; ++mi)
#pragma unroll
      for (int nj = 0; nj < 4; ++nj)
        acc[mi][nj] = MFMA16(af[mi], bfr[nj], acc[mi][nj]);
    __builtin_amdgcn_s_setprio(0);
    __builtin_amdgcn_s_barrier();

    // ---- phase 1: read A frags mi4..7
    bf16x8 af2[4];
#pragma unroll
    for (int mi = 0; mi < 4; ++mi)
      af2[mi] = *(const bf16x8*)&Asb[swz_addr(wr * 128 + (mi + 4) * 16 + lr, lg * 8)];
    __builtin_amdgcn_s_barrier();
    __builtin_amdgcn_s_setprio(1);
#pragma unroll
    for (int mi = 0; mi < 4; ++mi)
#pragma unroll
      for (int nj = 0; nj < 4; ++nj)
        acc[mi + 4][nj] = MFMA16(af2[mi], bfr[nj], acc[mi + 4][nj]);
    __builtin_amdgcn_s_setprio(0);
    if (kt + 1 < nK) asm volatile("s_waitcnt vmcnt(0)" ::: "memory");
    __builtin_amdgcn_s_barrier();
  }

  // epilogue: D row = (lane>>4)*4 + r, col = lane&15 (m89-verified layout)
#pragma unroll
  for (int nj = 0; nj < 4; ++nj) {
    const int col = bn0 + wc * 64 + nj * 16 + lr;
    const float bv = bias[col];
    const float sc = (QKV_SCALE && col < DIMC) ? SCALE : 1.0f;
#pragma unroll
    for (int mi = 0; mi < 8; ++mi) {
      const int row0 = bm0 + wr * 128 + mi * 16 + lg * 4;
#pragma unroll
      for (int r = 0; r < 4; ++r) {
        const float val = (acc[mi][nj][r] + bv) * sc;
        if (OUT_BF16)
          ((u16*)Cp)[(size_t)(row0 + r) * N + col] = f2bf(val);
        else
          ((float*)Cp)[(size_t)(row0 + r) * N + col] = val;
      }
    }
  }
}

// ---------------- fused window attention ----------------
// 1 wave per (window, head). qkv: [B_*49][1536] bf16 (q scaled already).
// biasmask: [64*16][64*64] fp32 (pad -1e30). out: [B_*49][512] bf16.
// V staged into LDS with coalesced 16B loads (replaces 32 scalar global loads).
__global__ void attn_win(const u16* __restrict__ qkv, const float* __restrict__ bmask,
                         u16* __restrict__ aout) {
  __shared__ u16 P[4][64 * 64];    // per-wave P tile, chunk-XOR swizzled
  __shared__ u16 Vs[4][64 * 40];   // per-wave V tile, row-major stride 40
  const int t = threadIdx.x, lane = t & 63, wv = t >> 6;
  const int lr = lane & 15, lg = lane >> 4;
  const int w = blockIdx.x >> 2;
  const int h = ((blockIdx.x & 3) << 2) + wv;
  const size_t base = (size_t)w * NTOK * 1536 + h * HEAD_DIM;

  const bf16x8 zf = {};
  bf16x8 qf[4], kf[4];
#pragma unroll
  for (int i = 0; i < 4; ++i) {
    const int row = i * 16 + lr;
    const size_t roff = base + (size_t)row * 1536 + lg * 8;
    qf[i] = (row < NTOK) ? *(const bf16x8*)&qkv[roff] : zf;          // Q(row, d..)
    kf[i] = (row < NTOK) ? *(const bf16x8*)&qkv[roff + DIMC] : zf;   // K(row, d..)
  }

  // issue V loads early (coalesced 16B); latency hides under QK^T + softmax
  u16x8 vreg[4];
  const u16x8 vz = {};
#pragma unroll
  for (int it = 0; it < 4; ++it) {
    const int k = it * 16 + (lane >> 2);
    const int seg = lane & 3;
    vreg[it] = (k < NTOK) ? *(const u16x8*)&qkv[base + 2 * DIMC + (size_t)k * 1536 + seg * 8]
                          : vz;
  }

  const f32x4 zc = {};
  f32x4 s[4][4];
  __builtin_amdgcn_s_setprio(1);
#pragma unroll
  for (int i = 0; i < 4; ++i)
#pragma unroll
    for (int j = 0; j < 4; ++j)
      s[i][j] = MFMA16(qf[i], kf[j], zc);   // S = (Q*scale) K^T
  __builtin_amdgcn_s_setprio(0);

  // park V in LDS (per-wave slice; per-wave lgkm ordering handled by compiler)
  u16* Vsw = &Vs[wv][0];
#pragma unroll
  for (int it = 0; it < 4; ++it) {
    const int k = it * 16 + (lane >> 2);
    const int seg = lane & 3;
    *(u16x8*)&Vsw[k * 40 + seg * 8] = vreg[it];
  }

  const float* bmp = bmask + (((size_t)(w & 63) * HEADS + h) << 12);
#pragma unroll
  for (int i = 0; i < 4; ++i)
#pragma unroll
    for (int r = 0; r < 4; ++r) {
      const int ii = i * 16 + lg * 4 + r;
#pragma unroll
      for (int j = 0; j < 4; ++j)
        s[i][j][r] += bmp[ii * 64 + j * 16 + lr];
    }

  // softmax over each row: 4 in-lane values x 16 lanes (shfl_xor 1,2,4,8)
#pragma unroll
  for (int i = 0; i < 4; ++i)
#pragma unroll
    for (int r = 0; r < 4; ++r) {
      float m = fmaxf(fmaxf(s[i][0][r], s[i][1][r]), fmaxf(s[i][2][r], s[i][3][r]));
      m = fmaxf(m, __shfl_xor(m, 1));
      m = fmaxf(m, __shfl_xor(m, 2));
      m = fmaxf(m, __shfl_xor(m, 4));
      m = fmaxf(m, __shfl_xor(m, 8));
      float sum = 0.f;
#pragma unroll
      for (int j = 0; j < 4; ++j) {
        const float e = __expf(s[i][j][r] - m);
        s[i][j][r] = e;
        sum += e;
      }
      sum += __shfl_xor(sum, 1);
      sum += __shfl_xor(sum, 2);
      sum += __shfl_xor(sum, 4);
      sum += __shfl_xor(sum, 8);
      const float rinv = __builtin_amdgcn_rcpf(sum);
#pragma unroll
      for (int j = 0; j < 4; ++j) s[i][j][r] *= rinv;
    }

  // P -> LDS (bf16), C/D layout scatter, chunk-XOR swizzled (stride 64)
  u16* Pw = &P[wv][0];
#pragma unroll
  for (int i = 0; i < 4; ++i)
#pragma unroll
    for (int r = 0; r < 4; ++r) {
      const int ii = i * 16 + lg * 4 + r;
#pragma unroll
      for (int j = 0; j < 4; ++j) {
        const int jj = j * 16 + lr;
        Pw[ii * 64 + (((jj >> 3) ^ (ii & 7)) << 3) + (jj & 7)] = f2bf(s[i][j][r]);
      }
    }

  // PV: out[i][d] = sum_k P[i][k] V[k][d]; K=64 (2 steps); V rows >=49 are 0
  f32x4 o[4][2] = {};
#pragma unroll
  for (int ks = 0; ks < 2; ++ks) {
    bf16x8 vf[2];
#pragma unroll
    for (int dn = 0; dn < 2; ++dn) {
#pragma unroll
      for (int e = 0; e < 8; ++e) {
        const int kk = ks * 32 + lg * 8 + e;
        vf[dn][e] = (short)Vsw[kk * 40 + dn * 16 + lr];
      }
    }
    __builtin_amdgcn_s_setprio(1);
#pragma unroll
    for (int i = 0; i < 4; ++i) {
      const int row = i * 16 + lr;
      const bf16x8 pa = *(const bf16x8*)&Pw[row * 64 + (((ks * 4 + lg) ^ (row & 7)) << 3)];
#pragma unroll
      for (int dn = 0; dn < 2; ++dn)
        o[i][dn] = MFMA16(pa, vf[dn], o[i][dn]);
    }
    __builtin_amdgcn_s_setprio(0);
  }

  // store attention output -> [token][h*32+d] bf16
#pragma unroll
  for (int i = 0; i < 4; ++i)
#pragma unroll
    for (int r = 0; r < 4; ++r) {
      const int row = i * 16 + lg * 4 + r;
      if (row < NTOK) {
        const size_t ob = ((size_t)w * NTOK + row) * DIMC + h * HEAD_DIM;
#pragma unroll
        for (int dn = 0; dn < 2; ++dn)
          aout[ob + dn * 16 + lr] = f2bf(o[i][dn][r]);
      }
    }
}

// ---------------- launch ----------------
extern "C" void kernel_launch(void* const* d_in, const int* in_sizes, int n_in,
                              void* d_out, int out_size, void* d_ws, size_t ws_size,
                              hipStream_t stream) {
  const float* x      = (const float*)d_in[0];   // (4096,49,512)
  const float* mask   = (const float*)d_in[1];   // (64,49,49)
  const float* qkv_w  = (const float*)d_in[2];   // (1536,512)
  const float* qkv_b  = (const float*)d_in[3];   // (1536,)
  const float* table  = (const float*)d_in[4];   // (169,16)
  const float* proj_w = (const float*)d_in[5];   // (512,512)
  const float* proj_b = (const float*)d_in[6];   // (512,)
  float* out = (float*)d_out;

  const int M = 4096 * NTOK;   // 200704

  char* ws = (char*)d_ws;
  u16*   qkv_bf   = (u16*)ws;                         // 200704*1536*2 = 616,562,688
  u16*   wqkv_bf  = (u16*)(ws + 616562688ull);        // 1536*512*2    = 1,572,864
  u16*   wproj_bf = (u16*)(ws + 618135552ull);        // 512*512*2     = 524,288
  float* biasmask = (float*)(ws + 618659840ull);      // 1024*4096*4   = 16,777,216
  // x_bf and attn_bf SHARE this region (disjoint lifetimes, same size):
  u16*   x_bf     = (u16*)(ws + 635437056ull);        // 200704*512*2  = 205,520,896
  u16*   attn_bf  = x_bf;
  // total 840,957,952 bytes

  cvt_f32_bf16<<<768, 256, 0, stream>>>(qkv_w, wqkv_bf, 1536 * 512);
  cvt_f32_bf16<<<256, 256, 0, stream>>>(proj_w, wproj_bf, 512 * 512);
  biasmask_kernel<<<1024, 256, 0, stream>>>(table, mask, biasmask);
  cvt_f32_bf16<<<1792, 256, 0, stream>>>(x, x_bf, M * DIMC);

  // QKV GEMM: (M,1536,512); grid 784*6 = 4704 (%8==0)
  gemm8<true, true><<<784 * 6, 512, 0, stream>>>(
      x_bf, wqkv_bf, qkv_b, qkv_bf, M, 1536, 512, 6);

  attn_win<<<4096 * 4, 256, 0, stream>>>(qkv_bf, biasmask, attn_bf);

  // proj GEMM: (M,512,512); grid 784*2 = 1568 (%8==0)
  gemm8<false, false><<<784 * 2, 512, 0, stream>>>(
      attn_bf, wproj_bf, proj_b, out, M, 512, 512, 2);
}